// Round 2
// baseline (1687.525 us; speedup 1.0000x reference)
//
#include <hip/hip_runtime.h>
#include <math.h>

#define N_NODES 16384
#define N_EDGES 32768
#define NGRAPH  512
#define DIM     64
#define NF      14
#define HIDN    128
#define EWCOLS  4096

typedef unsigned short u16;
typedef unsigned int   u32;
typedef __attribute__((ext_vector_type(8))) short bf16x8;
typedef __attribute__((ext_vector_type(4))) float f32x4;
typedef __attribute__((ext_vector_type(4))) u32   u32x4;

__device__ inline float b2f(u16 u){
    unsigned int x = ((unsigned int)u) << 16;
    return __builtin_bit_cast(float, x);
}
__device__ inline u16 f2b(float f){
    unsigned int x = __builtin_bit_cast(unsigned int, f);
    unsigned int r = (x + 0x7FFFu + ((x >> 16) & 1u)) >> 16;   // RNE
    return (u16)r;
}
__device__ inline float sigf(float x){ return 1.f / (1.f + expf(-x)); }
__device__ inline unsigned fkey(float f){
    unsigned u = __float_as_uint(f);
    return (u & 0x80000000u) ? ~u : (u | 0x80000000u);
}
__device__ inline float funkey(unsigned k){
    unsigned u = (k & 0x80000000u) ? (k & 0x7FFFFFFFu) : ~k;
    return __uint_as_float(u);
}

// out[n,f] = relu(x[n,:14] @ lin0_w + lin0_b)
__global__ __launch_bounds__(256) void k_lin0(const float* __restrict__ x,
        const float* __restrict__ w, const float* __restrict__ b, float* __restrict__ out){
    int n = (blockIdx.x * blockDim.x + threadIdx.x) >> 6;
    int lane = threadIdx.x & 63;
    if (n >= N_NODES) return;
    float xv = (lane < NF) ? x[n * NF + lane] : 0.f;
    float acc = b[lane];
    #pragma unroll
    for (int d = 0; d < NF; ++d){
        float xd = __shfl(xv, d);
        acc += xd * w[d * DIM + lane];
    }
    out[n * DIM + lane] = fmaxf(acc, 0.f);
}

// w2T[c,k] = bf16(nn2_w[k,c])   [4096,128] bf16
__global__ __launch_bounds__(256) void k_w2t(const float* __restrict__ w2, u16* __restrict__ w2T){
    int i = blockIdx.x * blockDim.x + threadIdx.x;
    if (i >= HIDN * EWCOLS) return;
    int k = i >> 12, c = i & 4095;
    w2T[c * HIDN + k] = f2b(w2[i]);
}

// transpose LSTM weights (fp32)
__global__ __launch_bounds__(256) void k_lstmT(const float* __restrict__ wih, const float* __restrict__ whh,
        float* __restrict__ wihT, float* __restrict__ whhT){
    int i = blockIdx.x * blockDim.x + threadIdx.x;
    if (i < 256*128){
        int j = i >> 7, d = i & 127;
        wihT[d*256 + j] = wih[i];
    } else if (i < 256*128 + 256*64){
        int i2 = i - 256*128;
        int j = i2 >> 6, d = i2 & 63;
        whhT[d*256 + j] = whh[i2];
    }
}

__global__ __launch_bounds__(256) void k_deg(const int* __restrict__ ei, unsigned* __restrict__ degu){
    int e = blockIdx.x * blockDim.x + threadIdx.x;
    if (e < N_EDGES) atomicAdd(&degu[ei[N_EDGES + e]], 1u);
}
__global__ __launch_bounds__(256) void k_dinv(const unsigned* __restrict__ degu, float* __restrict__ dinv){
    int n = blockIdx.x * blockDim.x + threadIdx.x;
    if (n < N_NODES) dinv[n] = 1.f / fmaxf((float)degu[n], 1.f);
}

// ---------------------------------------------------------------------------
// Fused per-round message kernel. Per 128-edge block:
//   t[e,:] = relu(ea[e]@nn1_w + nn1_b)           (bf16 into LDS)
//   for d in 0..63:  EW[e,f] = t[e,:] @ W2[:, d*64+f]   (MFMA, K=128)
//                    msg[e,f] += out[src_e,d] * (EW[e,f] + nn2_b[d*64+f])
//   atomicAdd(agg[dst_e, f], msg[e,f])
// ---------------------------------------------------------------------------
#define EB   128
#define LDT  136   // u16 stride (272 B = 17 x 16B slots -> conflict-free b128 col reads)
#define LDO  68    // f32 stride (272 B)

__global__ __launch_bounds__(512) void k_msg_fused(
        const int* __restrict__ ei, const float* __restrict__ ea,
        const float* __restrict__ w1, const float* __restrict__ b1,
        const u16* __restrict__ w2T, const float* __restrict__ b2,
        const float* __restrict__ out, float* __restrict__ agg)
{
    __shared__ u16   s_t[EB * LDT];        // 34816 B
    __shared__ float s_out[EB * LDO];      // 34816 B
    __shared__ u16   s_b[64 * 128];        // 16384 B, XOR-swizzled
    __shared__ float s_w1[4 * 128];
    __shared__ float s_b1[128];

    int tid = threadIdx.x;
    int e0 = blockIdx.x * EB;

    if (tid < 512) s_w1[tid & 511] = w1[tid & 511];
    if (tid < 128) s_b1[tid] = b1[tid];
    __syncthreads();

    {   // t tile on the fly (bf16) + out[src] tile
        int e = tid >> 2;
        int q = tid & 3;
        float4 av = *(const float4*)(ea + (size_t)(e0 + e) * 4);
        #pragma unroll 8
        for (int i = 0; i < 32; ++i){
            int h = q * 32 + i;
            float acc = s_b1[h] + av.x * s_w1[h] + av.y * s_w1[128 + h]
                      + av.z * s_w1[256 + h] + av.w * s_w1[384 + h];
            s_t[e * LDT + h] = f2b(fmaxf(acc, 0.f));
        }
        int s = ei[e0 + e];
        int p4 = q * 16;
        const float4* srcp = (const float4*)(out + (size_t)s * DIM + p4);
        float4 v0 = srcp[0], v1 = srcp[1], v2 = srcp[2], v3 = srcp[3];
        float* dst = s_out + e * LDO + p4;
        *(float4*)(dst)      = v0;
        *(float4*)(dst + 4)  = v1;
        *(float4*)(dst + 8)  = v2;
        *(float4*)(dst + 12) = v3;
    }
    __syncthreads();

    int wv   = tid >> 6;            // 8 waves: 4 row-groups x 2 col-groups
    int lane = tid & 63;
    int WR = (wv >> 1) * 32;
    int WC = (wv & 1) * 32;
    int lr = lane & 15;
    int lk = (lane >> 4) * 8;

    bf16x8 afr[2][4];
    #pragma unroll
    for (int m = 0; m < 2; ++m)
    #pragma unroll
    for (int kk = 0; kk < 4; ++kk)
        afr[m][kk] = *(const bf16x8*)(s_t + (WR + m*16 + lr) * LDT + kk*32 + lk);

    // B-chunk staging: thread -> (col, 2 slots of 16B)
    int bc = tid >> 3;
    int bs = tid & 7;
    const u32x4* gb = (const u32x4*)w2T;
    char* sb = (char*)s_b;
    u32x4 r0, r1;
    {
        size_t base = (size_t)bc << 4;       // chunk 0
        r0 = gb[base + bs*2];
        r1 = gb[base + bs*2 + 1];
    }

    f32x4 msg[2][2] = {};
    int swzr = (lr & 7) << 4;                // read-side XOR (col&7 == lr&7)
    int swzw = (bc & 7) << 4;                // write-side XOR

    for (int d = 0; d < 64; ++d){
        __syncthreads();                     // s_b consumed
        *(u32x4*)(sb + ((bc*256 + bs*32)      ^ swzw)) = r0;
        *(u32x4*)(sb + ((bc*256 + bs*32 + 16) ^ swzw)) = r1;
        if (d < 63){
            size_t base = ((size_t)(d+1)*64 + bc) << 4;
            r0 = gb[base + bs*2];
            r1 = gb[base + bs*2 + 1];
        }
        __syncthreads();                     // s_b ready

        f32x4 ew[2][2] = {};
        #pragma unroll
        for (int kk = 0; kk < 4; ++kk){
            int kb = kk*64 + (lane >> 4) * 16;
            bf16x8 bf0 = *(const bf16x8*)(sb + (((WC + lr)*256 + kb)      ^ swzr));
            bf16x8 bf1 = *(const bf16x8*)(sb + (((WC + 16 + lr)*256 + kb) ^ swzr));
            ew[0][0] = __builtin_amdgcn_mfma_f32_16x16x32_bf16(afr[0][kk], bf0, ew[0][0], 0, 0, 0);
            ew[0][1] = __builtin_amdgcn_mfma_f32_16x16x32_bf16(afr[0][kk], bf1, ew[0][1], 0, 0, 0);
            ew[1][0] = __builtin_amdgcn_mfma_f32_16x16x32_bf16(afr[1][kk], bf0, ew[1][0], 0, 0, 0);
            ew[1][1] = __builtin_amdgcn_mfma_f32_16x16x32_bf16(afr[1][kk], bf1, ew[1][1], 0, 0, 0);
        }
        int f0 = d*64 + WC + lr;
        float b2v0 = b2[f0], b2v1 = b2[f0 + 16];
        int crow = (lane >> 4) * 4;
        #pragma unroll
        for (int m = 0; m < 2; ++m){
            #pragma unroll
            for (int r = 0; r < 4; ++r){
                float sc = s_out[(WR + m*16 + crow + r) * LDO + d];
                msg[m][0][r] += sc * (ew[m][0][r] + b2v0);
                msg[m][1][r] += sc * (ew[m][1][r] + b2v1);
            }
        }
    }

    int crow = (lane >> 4) * 4, ccol = lane & 15;
    #pragma unroll
    for (int m = 0; m < 2; ++m){
        #pragma unroll
        for (int r = 0; r < 4; ++r){
            int eg = e0 + WR + m*16 + crow + r;
            int dn = ei[N_EDGES + eg];
            atomicAdd(&agg[(size_t)dn * DIM + WC + ccol],      msg[m][0][r]);
            atomicAdd(&agg[(size_t)dn * DIM + WC + 16 + ccol], msg[m][1][r]);
        }
    }
}

// fused NNConv root+mean-aggr+relu and GRU cell; in-place update of out
__global__ __launch_bounds__(512) void k_update(const float* __restrict__ rootw, const float* __restrict__ convb,
        const float* __restrict__ wih, const float* __restrict__ bih,
        const float* __restrict__ whh, const float* __restrict__ bhh,
        const float* __restrict__ agg, const float* __restrict__ dinv, float* __restrict__ out){
    __shared__ float s_root[64 * 65];
    __shared__ float s_wih[192 * 65];
    __shared__ float s_whh[192 * 65];
    int tid = threadIdx.x;
    for (int i = tid; i < 64*64;  i += 512) s_root[i + (i >> 6)] = rootw[i];
    for (int i = tid; i < 192*64; i += 512) s_wih[i + (i >> 6)]  = wih[i];
    for (int i = tid; i < 192*64; i += 512) s_whh[i + (i >> 6)]  = whh[i];
    __syncthreads();
    int lane = tid & 63;
    int wv = tid >> 6;
    for (int it = 0; it < 8; ++it){
        int n = blockIdx.x * 64 + wv * 8 + it;
        float h = out[n * DIM + lane];
        float macc = agg[n * DIM + lane] * dinv[n] + convb[lane];
        #pragma unroll
        for (int d = 0; d < 64; ++d){
            float hd = __shfl(h, d);
            macc += hd * s_root[d * 65 + lane];
        }
        float m = fmaxf(macc, 0.f);
        float gr = bih[lane],       hr = bhh[lane];
        float gz = bih[64 + lane],  hz = bhh[64 + lane];
        float gn = bih[128 + lane], hn = bhh[128 + lane];
        #pragma unroll
        for (int d = 0; d < 64; ++d){
            float md = __shfl(m, d);
            float hd = __shfl(h, d);
            gr += md * s_wih[lane * 65 + d];
            gz += md * s_wih[(64 + lane) * 65 + d];
            gn += md * s_wih[(128 + lane) * 65 + d];
            hr += hd * s_whh[lane * 65 + d];
            hz += hd * s_whh[(64 + lane) * 65 + d];
            hn += hd * s_whh[(128 + lane) * 65 + d];
        }
        float r  = sigf(gr + hr);
        float z  = sigf(gz + hz);
        float ng = tanhf(gn + r * hn);
        out[n * DIM + lane] = (1.f - z) * ng + z * h;
    }
}

// one LSTM cell step over all B graphs; block per graph
__global__ __launch_bounds__(256) void k_lstm(const float* __restrict__ qstar,
        const float* __restrict__ wihT, const float* __restrict__ bih,
        const float* __restrict__ whhT, const float* __restrict__ bhh,
        float* __restrict__ hl, float* __restrict__ cl){
    __shared__ float s_in[128];
    __shared__ float s_h[64];
    __shared__ float s_g[256];
    int g = blockIdx.x, j = threadIdx.x;
    if (j < 128) s_in[j] = qstar[g * 128 + j];
    if (j < 64)  s_h[j]  = hl[g * 64 + j];
    __syncthreads();
    float acc = bih[j] + bhh[j];
    #pragma unroll 8
    for (int d = 0; d < 128; ++d) acc += s_in[d] * wihT[d * 256 + j];
    #pragma unroll 8
    for (int d = 0; d < 64;  ++d) acc += s_h[d]  * whhT[d * 256 + j];
    s_g[j] = acc;
    __syncthreads();
    if (j < 64){
        float c = sigf(s_g[64 + j]) * cl[g * 64 + j] + sigf(s_g[j]) * tanhf(s_g[128 + j]);
        float h = sigf(s_g[192 + j]) * tanhf(c);
        cl[g * 64 + j] = c;
        hl[g * 64 + j] = h;
    }
}

__global__ __launch_bounds__(256) void k_s2s_init(unsigned* __restrict__ emax,
        float* __restrict__ esum, float* __restrict__ rbuf){
    int i = blockIdx.x * blockDim.x + threadIdx.x;
    if (i < NGRAPH){ emax[i] = 0x007FFFFFu; esum[i] = 0.f; }
    if (i < NGRAPH * DIM) rbuf[i] = 0.f;
}

__global__ __launch_bounds__(256) void k_score(const float* __restrict__ out, const float* __restrict__ hl,
        const int* __restrict__ batch, float* __restrict__ ebuf, unsigned* __restrict__ emax){
    int n = (blockIdx.x * blockDim.x + threadIdx.x) >> 6;
    int lane = threadIdx.x & 63;
    if (n >= N_NODES) return;
    int g = batch[n];
    float v = out[n * DIM + lane] * hl[g * DIM + lane];
    #pragma unroll
    for (int off = 32; off; off >>= 1) v += __shfl_down(v, off);
    if (lane == 0){
        ebuf[n] = v;
        atomicMax(&emax[g], fkey(v));
    }
}

__global__ __launch_bounds__(256) void k_exp(const float* __restrict__ ebuf, const int* __restrict__ batch,
        const unsigned* __restrict__ emax, float* __restrict__ exbuf, float* __restrict__ esum){
    int n = blockIdx.x * blockDim.x + threadIdx.x;
    if (n >= N_NODES) return;
    int g = batch[n];
    float ex = expf(ebuf[n] - funkey(emax[g]));
    exbuf[n] = ex;
    atomicAdd(&esum[g], ex);
}

__global__ __launch_bounds__(256) void k_rsum(const float* __restrict__ out, const float* __restrict__ exbuf,
        const float* __restrict__ esum, const int* __restrict__ batch, float* __restrict__ rbuf){
    int n = (blockIdx.x * blockDim.x + threadIdx.x) >> 6;
    int lane = threadIdx.x & 63;
    if (n >= N_NODES) return;
    int g = batch[n];
    float a = exbuf[n] / fmaxf(esum[g], 1e-16f);
    atomicAdd(&rbuf[g * DIM + lane], a * out[n * DIM + lane]);
}

__global__ __launch_bounds__(256) void k_qstar(const float* __restrict__ hl, const float* __restrict__ rbuf,
        float* __restrict__ qstar){
    int idx = blockIdx.x * blockDim.x + threadIdx.x;
    if (idx >= NGRAPH * 128) return;
    int g = idx >> 7, d = idx & 127;
    qstar[idx] = (d < 64) ? hl[g * 64 + d] : rbuf[g * 64 + (d - 64)];
}

__global__ __launch_bounds__(256) void k_final(const float* __restrict__ qstar,
        const float* __restrict__ w1, const float* __restrict__ b1,
        const float* __restrict__ w2, const float* __restrict__ b2, float* __restrict__ y){
    int g = (blockIdx.x * blockDim.x + threadIdx.x) >> 6;
    int lane = threadIdx.x & 63;
    if (g >= NGRAPH) return;
    float q0 = qstar[g * 128 + lane];
    float q1 = qstar[g * 128 + 64 + lane];
    float acc = b1[lane];
    #pragma unroll
    for (int d = 0; d < 64; ++d){
        acc += __shfl(q0, d) * w1[d * 64 + lane];
        acc += __shfl(q1, d) * w1[(64 + d) * 64 + lane];
    }
    float h = fmaxf(acc, 0.f);
    float p = h * w2[lane];
    #pragma unroll
    for (int off = 32; off; off >>= 1) p += __shfl_down(p, off);
    if (lane == 0) y[g] = p + b2[0];
}

extern "C" void kernel_launch(void* const* d_in, const int* in_sizes, int n_in,
                              void* d_out, int out_size, void* d_ws, size_t ws_size,
                              hipStream_t stream){
    const float* x      = (const float*)d_in[0];
    const int*   ei     = (const int*)d_in[1];
    const float* ea     = (const float*)d_in[2];
    const int*   batch  = (const int*)d_in[3];
    const float* lin0_w = (const float*)d_in[6];
    const float* lin0_b = (const float*)d_in[7];
    const float* nn1_w  = (const float*)d_in[8];
    const float* nn1_b  = (const float*)d_in[9];
    const float* nn2_w  = (const float*)d_in[10];
    const float* nn2_b  = (const float*)d_in[11];
    const float* root_w = (const float*)d_in[12];
    const float* conv_b = (const float*)d_in[13];
    const float* gwih   = (const float*)d_in[14];
    const float* gwhh   = (const float*)d_in[15];
    const float* gbih   = (const float*)d_in[16];
    const float* gbhh   = (const float*)d_in[17];
    const float* lwih   = (const float*)d_in[18];
    const float* lwhh   = (const float*)d_in[19];
    const float* lbih   = (const float*)d_in[20];
    const float* lbhh   = (const float*)d_in[21];
    const float* l1w    = (const float*)d_in[22];
    const float* l1b    = (const float*)d_in[23];
    const float* l2w    = (const float*)d_in[24];
    const float* l2b    = (const float*)d_in[25];
    float* y = (float*)d_out;

    char* p = (char*)d_ws;
    float* out   = (float*)p;    p += (size_t)N_NODES * DIM * 4;      // 4 MB
    float* agg   = (float*)p;    p += (size_t)N_NODES * DIM * 4;      // 4 MB
    u16* w2T     = (u16*)p;      p += (size_t)EWCOLS * HIDN * 2;      // 1 MB
    float* wihT  = (float*)p;    p += 128 * 256 * 4;
    float* whhT  = (float*)p;    p += 64 * 256 * 4;
    unsigned* degu = (unsigned*)p; p += N_NODES * 4;
    float* dinv  = (float*)p;    p += N_NODES * 4;
    float* ebuf  = (float*)p;    p += N_NODES * 4;
    float* exbuf = (float*)p;    p += N_NODES * 4;
    float* qstar = (float*)p;    p += NGRAPH * 128 * 4;
    float* hl    = (float*)p;    p += NGRAPH * 64 * 4;
    float* cl    = (float*)p;    p += NGRAPH * 64 * 4;
    float* rbuf  = (float*)p;    p += NGRAPH * 64 * 4;
    unsigned* emax = (unsigned*)p; p += NGRAPH * 4;
    float* esum  = (float*)p;    p += NGRAPH * 4;

    if ((size_t)(p - (char*)d_ws) > ws_size) return;  // needs ~10.6 MB

    hipMemsetAsync(degu,  0, N_NODES * 4, stream);
    hipMemsetAsync(qstar, 0, NGRAPH * 128 * 4, stream);
    hipMemsetAsync(hl,    0, NGRAPH * 64 * 4, stream);
    hipMemsetAsync(cl,    0, NGRAPH * 64 * 4, stream);

    k_lin0 <<<N_NODES / 4, 256, 0, stream>>>(x, lin0_w, lin0_b, out);
    k_w2t  <<<(HIDN * EWCOLS) / 256, 256, 0, stream>>>(nn2_w, w2T);
    k_lstmT<<<(256 * 128 + 256 * 64) / 256, 256, 0, stream>>>(lwih, lwhh, wihT, whhT);
    k_deg  <<<N_EDGES / 256, 256, 0, stream>>>(ei, degu);
    k_dinv <<<N_NODES / 256, 256, 0, stream>>>(degu, dinv);

    for (int r = 0; r < 3; ++r){
        hipMemsetAsync(agg, 0, (size_t)N_NODES * DIM * 4, stream);
        k_msg_fused<<<N_EDGES / EB, 512, 0, stream>>>(ei, ea, nn1_w, nn1_b, w2T, nn2_b, out, agg);
        k_update   <<<256, 512, 0, stream>>>(root_w, conv_b, gwih, gbih, gwhh, gbhh, agg, dinv, out);
    }

    for (int s = 0; s < 3; ++s){
        k_lstm    <<<NGRAPH, 256, 0, stream>>>(qstar, wihT, lbih, whhT, lbhh, hl, cl);
        k_s2s_init<<<(NGRAPH * DIM) / 256, 256, 0, stream>>>(emax, esum, rbuf);
        k_score   <<<N_NODES / 4, 256, 0, stream>>>(out, hl, batch, ebuf, emax);
        k_exp     <<<N_NODES / 256, 256, 0, stream>>>(ebuf, batch, emax, exbuf, esum);
        k_rsum    <<<N_NODES / 4, 256, 0, stream>>>(out, exbuf, esum, batch, rbuf);
        k_qstar   <<<(NGRAPH * 128) / 256, 256, 0, stream>>>(hl, rbuf, qstar);
    }
    k_final<<<NGRAPH / 4, 256, 0, stream>>>(qstar, l1w, l1b, l2w, l2b, y);
}

// Round 3
// 397.458 us; speedup vs baseline: 4.2458x; 4.2458x over previous
//
#include <hip/hip_runtime.h>
#include <math.h>

#define N_NODES 16384
#define N_EDGES 32768
#define NGRAPH  512
#define DIM     64
#define NF      14
#define HIDN    128
#define EWCOLS  4096

typedef unsigned short u16;
typedef unsigned int   u32;
typedef __attribute__((ext_vector_type(8))) short bf16x8;
typedef __attribute__((ext_vector_type(4))) float f32x4;
typedef __attribute__((ext_vector_type(4))) u32   u32x4;

__device__ inline float b2f(u16 u){
    unsigned int x = ((unsigned int)u) << 16;
    return __builtin_bit_cast(float, x);
}
__device__ inline u16 f2b(float f){
    unsigned int x = __builtin_bit_cast(unsigned int, f);
    unsigned int r = (x + 0x7FFFu + ((x >> 16) & 1u)) >> 16;   // RNE
    return (u16)r;
}
__device__ inline float sigf(float x){ return 1.f / (1.f + expf(-x)); }
__device__ inline unsigned fkey(float f){
    unsigned u = __float_as_uint(f);
    return (u & 0x80000000u) ? ~u : (u | 0x80000000u);
}
__device__ inline float funkey(unsigned k){
    unsigned u = (k & 0x80000000u) ? (k & 0x7FFFFFFFu) : ~k;
    return __uint_as_float(u);
}

// out[n,f] = relu(x[n,:14] @ lin0_w + lin0_b)
__global__ __launch_bounds__(256) void k_lin0(const float* __restrict__ x,
        const float* __restrict__ w, const float* __restrict__ b, float* __restrict__ out){
    int n = (blockIdx.x * blockDim.x + threadIdx.x) >> 6;
    int lane = threadIdx.x & 63;
    if (n >= N_NODES) return;
    float xv = (lane < NF) ? x[n * NF + lane] : 0.f;
    float acc = b[lane];
    #pragma unroll
    for (int d = 0; d < NF; ++d){
        float xd = __shfl(xv, d);
        acc += xd * w[d * DIM + lane];
    }
    out[n * DIM + lane] = fmaxf(acc, 0.f);
}

// w2T[c,k] = bf16(nn2_w[k,c])   [4096,128] bf16
__global__ __launch_bounds__(256) void k_w2t(const float* __restrict__ w2, u16* __restrict__ w2T){
    int i = blockIdx.x * blockDim.x + threadIdx.x;
    if (i >= HIDN * EWCOLS) return;
    int k = i >> 12, c = i & 4095;
    w2T[c * HIDN + k] = f2b(w2[i]);
}

// transpose LSTM weights (fp32)
__global__ __launch_bounds__(256) void k_lstmT(const float* __restrict__ wih, const float* __restrict__ whh,
        float* __restrict__ wihT, float* __restrict__ whhT){
    int i = blockIdx.x * blockDim.x + threadIdx.x;
    if (i < 256*128){
        int j = i >> 7, d = i & 127;
        wihT[d*256 + j] = wih[i];
    } else if (i < 256*128 + 256*64){
        int i2 = i - 256*128;
        int j = i2 >> 6, d = i2 & 63;
        whhT[d*256 + j] = whh[i2];
    }
}

// split GRU weights into bf16 hi/lo pairs; rootT transposed, wih/whh kept row-major
__global__ __launch_bounds__(256) void k_wsplit(const float* __restrict__ root,
        const float* __restrict__ wih, const float* __restrict__ whh,
        u16* __restrict__ rtHi, u16* __restrict__ rtLo,
        u16* __restrict__ wihHi, u16* __restrict__ wihLo,
        u16* __restrict__ whhHi, u16* __restrict__ whhLo){
    int i = blockIdx.x * blockDim.x + threadIdx.x;
    if (i < 4096){
        int d = i >> 6, j = i & 63;
        float v = root[i];                  // root[d][j]
        u16 h = f2b(v);
        rtHi[j*64 + d] = h;
        rtLo[j*64 + d] = f2b(v - b2f(h));
    } else if (i < 4096 + 12288){
        int k = i - 4096;
        float v = wih[k];
        u16 h = f2b(v);
        wihHi[k] = h; wihLo[k] = f2b(v - b2f(h));
    } else if (i < 4096 + 24576){
        int k = i - 4096 - 12288;
        float v = whh[k];
        u16 h = f2b(v);
        whhHi[k] = h; whhLo[k] = f2b(v - b2f(h));
    }
}

__global__ __launch_bounds__(256) void k_deg(const int* __restrict__ ei, unsigned* __restrict__ degu){
    int e = blockIdx.x * blockDim.x + threadIdx.x;
    if (e < N_EDGES) atomicAdd(&degu[ei[N_EDGES + e]], 1u);
}
__global__ __launch_bounds__(256) void k_dinv(const unsigned* __restrict__ degu, float* __restrict__ dinv){
    int n = blockIdx.x * blockDim.x + threadIdx.x;
    if (n < N_NODES) dinv[n] = 1.f / fmaxf((float)degu[n], 1.f);
}

// ---------------------------------------------------------------------------
// Fused per-round message kernel (unchanged from round 2, passing).
// ---------------------------------------------------------------------------
#define EB   128
#define LDT  136
#define LDO  68

__global__ __launch_bounds__(512) void k_msg_fused(
        const int* __restrict__ ei, const float* __restrict__ ea,
        const float* __restrict__ w1, const float* __restrict__ b1,
        const u16* __restrict__ w2T, const float* __restrict__ b2,
        const float* __restrict__ out, float* __restrict__ agg)
{
    __shared__ u16   s_t[EB * LDT];
    __shared__ float s_out[EB * LDO];
    __shared__ u16   s_b[64 * 128];
    __shared__ float s_w1[4 * 128];
    __shared__ float s_b1[128];

    int tid = threadIdx.x;
    int e0 = blockIdx.x * EB;

    if (tid < 512) s_w1[tid & 511] = w1[tid & 511];
    if (tid < 128) s_b1[tid] = b1[tid];
    __syncthreads();

    {
        int e = tid >> 2;
        int q = tid & 3;
        float4 av = *(const float4*)(ea + (size_t)(e0 + e) * 4);
        #pragma unroll 8
        for (int i = 0; i < 32; ++i){
            int h = q * 32 + i;
            float acc = s_b1[h] + av.x * s_w1[h] + av.y * s_w1[128 + h]
                      + av.z * s_w1[256 + h] + av.w * s_w1[384 + h];
            s_t[e * LDT + h] = f2b(fmaxf(acc, 0.f));
        }
        int s = ei[e0 + e];
        int p4 = q * 16;
        const float4* srcp = (const float4*)(out + (size_t)s * DIM + p4);
        float4 v0 = srcp[0], v1 = srcp[1], v2 = srcp[2], v3 = srcp[3];
        float* dst = s_out + e * LDO + p4;
        *(float4*)(dst)      = v0;
        *(float4*)(dst + 4)  = v1;
        *(float4*)(dst + 8)  = v2;
        *(float4*)(dst + 12) = v3;
    }
    __syncthreads();

    int wv   = tid >> 6;
    int lane = tid & 63;
    int WR = (wv >> 1) * 32;
    int WC = (wv & 1) * 32;
    int lr = lane & 15;
    int lk = (lane >> 4) * 8;

    bf16x8 afr[2][4];
    #pragma unroll
    for (int m = 0; m < 2; ++m)
    #pragma unroll
    for (int kk = 0; kk < 4; ++kk)
        afr[m][kk] = *(const bf16x8*)(s_t + (WR + m*16 + lr) * LDT + kk*32 + lk);

    int bc = tid >> 3;
    int bs = tid & 7;
    const u32x4* gb = (const u32x4*)w2T;
    char* sb = (char*)s_b;
    u32x4 r0, r1;
    {
        size_t base = (size_t)bc << 4;
        r0 = gb[base + bs*2];
        r1 = gb[base + bs*2 + 1];
    }

    f32x4 msg[2][2] = {};
    int swzr = (lr & 7) << 4;
    int swzw = (bc & 7) << 4;

    for (int d = 0; d < 64; ++d){
        __syncthreads();
        *(u32x4*)(sb + ((bc*256 + bs*32)      ^ swzw)) = r0;
        *(u32x4*)(sb + ((bc*256 + bs*32 + 16) ^ swzw)) = r1;
        if (d < 63){
            size_t base = ((size_t)(d+1)*64 + bc) << 4;
            r0 = gb[base + bs*2];
            r1 = gb[base + bs*2 + 1];
        }
        __syncthreads();

        f32x4 ew[2][2] = {};
        #pragma unroll
        for (int kk = 0; kk < 4; ++kk){
            int kb = kk*64 + (lane >> 4) * 16;
            bf16x8 bf0 = *(const bf16x8*)(sb + (((WC + lr)*256 + kb)      ^ swzr));
            bf16x8 bf1 = *(const bf16x8*)(sb + (((WC + 16 + lr)*256 + kb) ^ swzr));
            ew[0][0] = __builtin_amdgcn_mfma_f32_16x16x32_bf16(afr[0][kk], bf0, ew[0][0], 0, 0, 0);
            ew[0][1] = __builtin_amdgcn_mfma_f32_16x16x32_bf16(afr[0][kk], bf1, ew[0][1], 0, 0, 0);
            ew[1][0] = __builtin_amdgcn_mfma_f32_16x16x32_bf16(afr[1][kk], bf0, ew[1][0], 0, 0, 0);
            ew[1][1] = __builtin_amdgcn_mfma_f32_16x16x32_bf16(afr[1][kk], bf1, ew[1][1], 0, 0, 0);
        }
        int f0 = d*64 + WC + lr;
        float b2v0 = b2[f0], b2v1 = b2[f0 + 16];
        int crow = (lane >> 4) * 4;
        #pragma unroll
        for (int m = 0; m < 2; ++m){
            #pragma unroll
            for (int r = 0; r < 4; ++r){
                float sc = s_out[(WR + m*16 + crow + r) * LDO + d];
                msg[m][0][r] += sc * (ew[m][0][r] + b2v0);
                msg[m][1][r] += sc * (ew[m][1][r] + b2v1);
            }
        }
    }

    int crow = (lane >> 4) * 4, ccol = lane & 15;
    #pragma unroll
    for (int m = 0; m < 2; ++m){
        #pragma unroll
        for (int r = 0; r < 4; ++r){
            int eg = e0 + WR + m*16 + crow + r;
            int dn = ei[N_EDGES + eg];
            atomicAdd(&agg[(size_t)dn * DIM + WC + ccol],      msg[m][0][r]);
            atomicAdd(&agg[(size_t)dn * DIM + WC + 16 + ccol], msg[m][1][r]);
        }
    }
}

// ---------------------------------------------------------------------------
// k_update rewritten: MFMA with bf16x2 (hi+lo) precision splitting.
// Block = 256 threads (4 waves), 64 nodes. Wave w owns 16-row tile.
//   stage1: M = relu(H@rootT^T + agg*dinv + convb)
//   stage2: Gi = M@wih^T, Gh = H@whh^T  (separate accs; n-gate needs both)
//   GRU elementwise in fp32, in-place update of out.
// ---------------------------------------------------------------------------
#define LDH 68
__global__ __launch_bounds__(256) void k_update(
        const u16* __restrict__ rtHi, const u16* __restrict__ rtLo,
        const u16* __restrict__ wihHi, const u16* __restrict__ wihLo,
        const u16* __restrict__ whhHi, const u16* __restrict__ whhLo,
        const float* __restrict__ convb, const float* __restrict__ bih,
        const float* __restrict__ bhh,
        const float* __restrict__ agg, const float* __restrict__ dinv,
        float* __restrict__ out)
{
    __shared__ float s_h[64 * LDH];
    __shared__ float s_aux[64 * LDH];
    __shared__ float s_m[64 * LDH];
    int tid = threadIdx.x;
    int n0 = blockIdx.x * 64;

    {   // coalesced stage of H and (agg*dinv + convb)
        int row = tid >> 2, cb = (tid & 3) * 16;
        const float4* hp = (const float4*)(out + (size_t)(n0 + row) * DIM + cb);
        const float4* ap = (const float4*)(agg + (size_t)(n0 + row) * DIM + cb);
        float di = dinv[n0 + row];
        #pragma unroll
        for (int q = 0; q < 4; ++q){
            float4 hv = hp[q];
            float4 av = ap[q];
            *(float4*)(s_h + row * LDH + cb + q*4) = hv;
            float4 xv;
            xv.x = av.x * di + convb[cb + q*4 + 0];
            xv.y = av.y * di + convb[cb + q*4 + 1];
            xv.z = av.z * di + convb[cb + q*4 + 2];
            xv.w = av.w * di + convb[cb + q*4 + 3];
            *(float4*)(s_aux + row * LDH + cb + q*4) = xv;
        }
    }
    __syncthreads();

    int wv = tid >> 6, lane = tid & 63;
    int lr = lane & 15, lkb = (lane >> 4) * 8;
    int arow = wv * 16 + lr;

    // H A-fragments (hi/lo)
    bf16x8 hHi[2], hLo[2];
    #pragma unroll
    for (int kk = 0; kk < 2; ++kk){
        const float* src = s_h + arow * LDH + kk*32 + lkb;
        bf16x8 hi8, lo8;
        #pragma unroll
        for (int e = 0; e < 8; ++e){
            float v = src[e];
            u16 h = f2b(v);
            hi8[e] = (short)h;
            lo8[e] = (short)f2b(v - b2f(h));
        }
        hHi[kk] = hi8; hLo[kk] = lo8;
    }

    // stage1: C1 = H @ root   (rootT[j][d] layout, B-frag = rtX[(ct*16+lr)*64 + k])
    f32x4 c1[4] = {};
    #pragma unroll
    for (int ct = 0; ct < 4; ++ct){
        #pragma unroll
        for (int kk = 0; kk < 2; ++kk){
            int off = (ct*16 + lr) * 64 + kk*32 + lkb;
            bf16x8 bHi = *(const bf16x8*)(rtHi + off);
            bf16x8 bLo = *(const bf16x8*)(rtLo + off);
            c1[ct] = __builtin_amdgcn_mfma_f32_16x16x32_bf16(hHi[kk], bHi, c1[ct], 0, 0, 0);
            c1[ct] = __builtin_amdgcn_mfma_f32_16x16x32_bf16(hLo[kk], bHi, c1[ct], 0, 0, 0);
            c1[ct] = __builtin_amdgcn_mfma_f32_16x16x32_bf16(hHi[kk], bLo, c1[ct], 0, 0, 0);
        }
    }

    // M = relu(C1 + aux) -> LDS
    int crow = (lane >> 4) * 4;
    #pragma unroll
    for (int ct = 0; ct < 4; ++ct){
        #pragma unroll
        for (int r = 0; r < 4; ++r){
            int row = wv*16 + crow + r;
            int col = ct*16 + lr;
            float m = fmaxf(c1[ct][r] + s_aux[row * LDH + col], 0.f);
            s_m[row * LDH + col] = m;
        }
    }
    __syncthreads();

    // M A-fragments (hi/lo)
    bf16x8 mHi[2], mLo[2];
    #pragma unroll
    for (int kk = 0; kk < 2; ++kk){
        const float* src = s_m + arow * LDH + kk*32 + lkb;
        bf16x8 hi8, lo8;
        #pragma unroll
        for (int e = 0; e < 8; ++e){
            float v = src[e];
            u16 h = f2b(v);
            hi8[e] = (short)h;
            lo8[e] = (short)f2b(v - b2f(h));
        }
        mHi[kk] = hi8; mLo[kk] = lo8;
    }

    // stage2: Gi = M@wih^T, Gh = H@whh^T  (wih/whh row-major [192][64] = BT layout)
    f32x4 gi[12] = {}, gh[12] = {};
    #pragma unroll
    for (int ct = 0; ct < 12; ++ct){
        #pragma unroll
        for (int kk = 0; kk < 2; ++kk){
            int off = (ct*16 + lr) * 64 + kk*32 + lkb;
            bf16x8 biH = *(const bf16x8*)(wihHi + off);
            bf16x8 biL = *(const bf16x8*)(wihLo + off);
            gi[ct] = __builtin_amdgcn_mfma_f32_16x16x32_bf16(mHi[kk], biH, gi[ct], 0, 0, 0);
            gi[ct] = __builtin_amdgcn_mfma_f32_16x16x32_bf16(mLo[kk], biH, gi[ct], 0, 0, 0);
            gi[ct] = __builtin_amdgcn_mfma_f32_16x16x32_bf16(mHi[kk], biL, gi[ct], 0, 0, 0);
            bf16x8 bhH = *(const bf16x8*)(whhHi + off);
            bf16x8 bhL = *(const bf16x8*)(whhLo + off);
            gh[ct] = __builtin_amdgcn_mfma_f32_16x16x32_bf16(hHi[kk], bhH, gh[ct], 0, 0, 0);
            gh[ct] = __builtin_amdgcn_mfma_f32_16x16x32_bf16(hLo[kk], bhH, gh[ct], 0, 0, 0);
            gh[ct] = __builtin_amdgcn_mfma_f32_16x16x32_bf16(hHi[kk], bhL, gh[ct], 0, 0, 0);
        }
    }

    // GRU elementwise (fp32), write h' to s_aux
    #pragma unroll
    for (int ct = 0; ct < 4; ++ct){
        int col = ct*16 + lr;
        float br_i = bih[col],       br_h = bhh[col];
        float bz_i = bih[64 + col],  bz_h = bhh[64 + col];
        float bn_i = bih[128 + col], bn_h = bhh[128 + col];
        #pragma unroll
        for (int r = 0; r < 4; ++r){
            int row = wv*16 + crow + r;
            float rg = sigf(gi[ct][r] + br_i + gh[ct][r] + br_h);
            float zg = sigf(gi[ct+4][r] + bz_i + gh[ct+4][r] + bz_h);
            float ng = tanhf(gi[ct+8][r] + bn_i + rg * (gh[ct+8][r] + bn_h));
            float h  = s_h[row * LDH + col];
            s_aux[row * LDH + col] = (1.f - zg) * ng + zg * h;
        }
    }
    __syncthreads();

    {   // coalesced store
        int row = tid >> 2, cb = (tid & 3) * 16;
        #pragma unroll
        for (int q = 0; q < 4; ++q)
            *(float4*)(out + (size_t)(n0 + row) * DIM + cb + q*4) =
                *(const float4*)(s_aux + row * LDH + cb + q*4);
    }
}

// one LSTM cell step over all B graphs; block per graph
__global__ __launch_bounds__(256) void k_lstm(const float* __restrict__ qstar,
        const float* __restrict__ wihT, const float* __restrict__ bih,
        const float* __restrict__ whhT, const float* __restrict__ bhh,
        float* __restrict__ hl, float* __restrict__ cl){
    __shared__ float s_in[128];
    __shared__ float s_h[64];
    __shared__ float s_g[256];
    int g = blockIdx.x, j = threadIdx.x;
    if (j < 128) s_in[j] = qstar[g * 128 + j];
    if (j < 64)  s_h[j]  = hl[g * 64 + j];
    __syncthreads();
    float acc = bih[j] + bhh[j];
    #pragma unroll 8
    for (int d = 0; d < 128; ++d) acc += s_in[d] * wihT[d * 256 + j];
    #pragma unroll 8
    for (int d = 0; d < 64;  ++d) acc += s_h[d]  * whhT[d * 256 + j];
    s_g[j] = acc;
    __syncthreads();
    if (j < 64){
        float c = sigf(s_g[64 + j]) * cl[g * 64 + j] + sigf(s_g[j]) * tanhf(s_g[128 + j]);
        float h = sigf(s_g[192 + j]) * tanhf(c);
        cl[g * 64 + j] = c;
        hl[g * 64 + j] = h;
    }
}

__global__ __launch_bounds__(256) void k_s2s_init(unsigned* __restrict__ emax,
        float* __restrict__ esum, float* __restrict__ rbuf){
    int i = blockIdx.x * blockDim.x + threadIdx.x;
    if (i < NGRAPH){ emax[i] = 0x007FFFFFu; esum[i] = 0.f; }
    if (i < NGRAPH * DIM) rbuf[i] = 0.f;
}

__global__ __launch_bounds__(256) void k_score(const float* __restrict__ out, const float* __restrict__ hl,
        const int* __restrict__ batch, float* __restrict__ ebuf, unsigned* __restrict__ emax){
    int n = (blockIdx.x * blockDim.x + threadIdx.x) >> 6;
    int lane = threadIdx.x & 63;
    if (n >= N_NODES) return;
    int g = batch[n];
    float v = out[n * DIM + lane] * hl[g * DIM + lane];
    #pragma unroll
    for (int off = 32; off; off >>= 1) v += __shfl_down(v, off);
    if (lane == 0){
        ebuf[n] = v;
        atomicMax(&emax[g], fkey(v));
    }
}

__global__ __launch_bounds__(256) void k_exp(const float* __restrict__ ebuf, const int* __restrict__ batch,
        const unsigned* __restrict__ emax, float* __restrict__ exbuf, float* __restrict__ esum){
    int n = blockIdx.x * blockDim.x + threadIdx.x;
    if (n >= N_NODES) return;
    int g = batch[n];
    float ex = expf(ebuf[n] - funkey(emax[g]));
    exbuf[n] = ex;
    atomicAdd(&esum[g], ex);
}

__global__ __launch_bounds__(256) void k_rsum(const float* __restrict__ out, const float* __restrict__ exbuf,
        const float* __restrict__ esum, const int* __restrict__ batch, float* __restrict__ rbuf){
    int n = (blockIdx.x * blockDim.x + threadIdx.x) >> 6;
    int lane = threadIdx.x & 63;
    if (n >= N_NODES) return;
    int g = batch[n];
    float a = exbuf[n] / fmaxf(esum[g], 1e-16f);
    atomicAdd(&rbuf[g * DIM + lane], a * out[n * DIM + lane]);
}

__global__ __launch_bounds__(256) void k_qstar(const float* __restrict__ hl, const float* __restrict__ rbuf,
        float* __restrict__ qstar){
    int idx = blockIdx.x * blockDim.x + threadIdx.x;
    if (idx >= NGRAPH * 128) return;
    int g = idx >> 7, d = idx & 127;
    qstar[idx] = (d < 64) ? hl[g * 64 + d] : rbuf[g * 64 + (d - 64)];
}

__global__ __launch_bounds__(256) void k_final(const float* __restrict__ qstar,
        const float* __restrict__ w1, const float* __restrict__ b1,
        const float* __restrict__ w2, const float* __restrict__ b2, float* __restrict__ y){
    int g = (blockIdx.x * blockDim.x + threadIdx.x) >> 6;
    int lane = threadIdx.x & 63;
    if (g >= NGRAPH) return;
    float q0 = qstar[g * 128 + lane];
    float q1 = qstar[g * 128 + 64 + lane];
    float acc = b1[lane];
    #pragma unroll
    for (int d = 0; d < 64; ++d){
        acc += __shfl(q0, d) * w1[d * 64 + lane];
        acc += __shfl(q1, d) * w1[(64 + d) * 64 + lane];
    }
    float h = fmaxf(acc, 0.f);
    float p = h * w2[lane];
    #pragma unroll
    for (int off = 32; off; off >>= 1) p += __shfl_down(p, off);
    if (lane == 0) y[g] = p + b2[0];
}

extern "C" void kernel_launch(void* const* d_in, const int* in_sizes, int n_in,
                              void* d_out, int out_size, void* d_ws, size_t ws_size,
                              hipStream_t stream){
    const float* x      = (const float*)d_in[0];
    const int*   ei     = (const int*)d_in[1];
    const float* ea     = (const float*)d_in[2];
    const int*   batch  = (const int*)d_in[3];
    const float* lin0_w = (const float*)d_in[6];
    const float* lin0_b = (const float*)d_in[7];
    const float* nn1_w  = (const float*)d_in[8];
    const float* nn1_b  = (const float*)d_in[9];
    const float* nn2_w  = (const float*)d_in[10];
    const float* nn2_b  = (const float*)d_in[11];
    const float* root_w = (const float*)d_in[12];
    const float* conv_b = (const float*)d_in[13];
    const float* gwih   = (const float*)d_in[14];
    const float* gwhh   = (const float*)d_in[15];
    const float* gbih   = (const float*)d_in[16];
    const float* gbhh   = (const float*)d_in[17];
    const float* lwih   = (const float*)d_in[18];
    const float* lwhh   = (const float*)d_in[19];
    const float* lbih   = (const float*)d_in[20];
    const float* lbhh   = (const float*)d_in[21];
    const float* l1w    = (const float*)d_in[22];
    const float* l1b    = (const float*)d_in[23];
    const float* l2w    = (const float*)d_in[24];
    const float* l2b    = (const float*)d_in[25];
    float* y = (float*)d_out;

    char* p = (char*)d_ws;
    float* out   = (float*)p;    p += (size_t)N_NODES * DIM * 4;
    float* agg   = (float*)p;    p += (size_t)N_NODES * DIM * 4;
    u16* w2T     = (u16*)p;      p += (size_t)EWCOLS * HIDN * 2;
    float* wihT  = (float*)p;    p += 128 * 256 * 4;
    float* whhT  = (float*)p;    p += 64 * 256 * 4;
    u16* rtHi    = (u16*)p;      p += 4096 * 2;
    u16* rtLo    = (u16*)p;      p += 4096 * 2;
    u16* wihHi   = (u16*)p;      p += 12288 * 2;
    u16* wihLo   = (u16*)p;      p += 12288 * 2;
    u16* whhHi   = (u16*)p;      p += 12288 * 2;
    u16* whhLo   = (u16*)p;      p += 12288 * 2;
    unsigned* degu = (unsigned*)p; p += N_NODES * 4;
    float* dinv  = (float*)p;    p += N_NODES * 4;
    float* ebuf  = (float*)p;    p += N_NODES * 4;
    float* exbuf = (float*)p;    p += N_NODES * 4;
    float* qstar = (float*)p;    p += NGRAPH * 128 * 4;
    float* hl    = (float*)p;    p += NGRAPH * 64 * 4;
    float* cl    = (float*)p;    p += NGRAPH * 64 * 4;
    float* rbuf  = (float*)p;    p += NGRAPH * 64 * 4;
    unsigned* emax = (unsigned*)p; p += NGRAPH * 4;
    float* esum  = (float*)p;    p += NGRAPH * 4;

    if ((size_t)(p - (char*)d_ws) > ws_size) return;

    hipMemsetAsync(degu,  0, N_NODES * 4, stream);
    hipMemsetAsync(qstar, 0, NGRAPH * 128 * 4, stream);
    hipMemsetAsync(hl,    0, NGRAPH * 64 * 4, stream);
    hipMemsetAsync(cl,    0, NGRAPH * 64 * 4, stream);

    k_lin0  <<<N_NODES / 4, 256, 0, stream>>>(x, lin0_w, lin0_b, out);
    k_w2t   <<<(HIDN * EWCOLS) / 256, 256, 0, stream>>>(nn2_w, w2T);
    k_lstmT <<<(256 * 128 + 256 * 64) / 256, 256, 0, stream>>>(lwih, lwhh, wihT, whhT);
    k_wsplit<<<(4096 + 24576) / 256, 256, 0, stream>>>(root_w, gwih, gwhh,
                rtHi, rtLo, wihHi, wihLo, whhHi, whhLo);
    k_deg   <<<N_EDGES / 256, 256, 0, stream>>>(ei, degu);
    k_dinv  <<<N_NODES / 256, 256, 0, stream>>>(degu, dinv);

    for (int r = 0; r < 3; ++r){
        hipMemsetAsync(agg, 0, (size_t)N_NODES * DIM * 4, stream);
        k_msg_fused<<<N_EDGES / EB, 512, 0, stream>>>(ei, ea, nn1_w, nn1_b, w2T, nn2_b, out, agg);
        k_update   <<<N_NODES / 64, 256, 0, stream>>>(rtHi, rtLo, wihHi, wihLo, whhHi, whhLo,
                        conv_b, gbih, gbhh, agg, dinv, out);
    }

    for (int s = 0; s < 3; ++s){
        k_lstm    <<<NGRAPH, 256, 0, stream>>>(qstar, wihT, lbih, whhT, lbhh, hl, cl);
        k_s2s_init<<<(NGRAPH * DIM) / 256, 256, 0, stream>>>(emax, esum, rbuf);
        k_score   <<<N_NODES / 4, 256, 0, stream>>>(out, hl, batch, ebuf, emax);
        k_exp     <<<N_NODES / 256, 256, 0, stream>>>(ebuf, batch, emax, exbuf, esum);
        k_rsum    <<<N_NODES / 4, 256, 0, stream>>>(out, exbuf, esum, batch, rbuf);
        k_qstar   <<<(NGRAPH * 128) / 256, 256, 0, stream>>>(hl, rbuf, qstar);
    }
    k_final<<<NGRAPH / 4, 256, 0, stream>>>(qstar, l1w, l1b, l2w, l2b, y);
}

// Round 4
// 370.028 us; speedup vs baseline: 4.5605x; 1.0741x over previous
//
#include <hip/hip_runtime.h>
#include <math.h>

#define N_NODES 16384
#define N_EDGES 32768
#define NGRAPH  512
#define DIM     64
#define NF      14
#define HIDN    128
#define EWCOLS  4096

typedef unsigned short u16;
typedef unsigned int   u32;
typedef __attribute__((ext_vector_type(8))) short bf16x8;
typedef __attribute__((ext_vector_type(4))) float f32x4;
typedef __attribute__((ext_vector_type(4))) u32   u32x4;

__device__ inline float b2f(u16 u){
    unsigned int x = ((unsigned int)u) << 16;
    return __builtin_bit_cast(float, x);
}
__device__ inline u16 f2b(float f){
    unsigned int x = __builtin_bit_cast(unsigned int, f);
    unsigned int r = (x + 0x7FFFu + ((x >> 16) & 1u)) >> 16;   // RNE
    return (u16)r;
}
__device__ inline float sigf(float x){ return 1.f / (1.f + expf(-x)); }

// out[n,f] = relu(x[n,:14] @ lin0_w + lin0_b)
__global__ __launch_bounds__(256) void k_lin0(const float* __restrict__ x,
        const float* __restrict__ w, const float* __restrict__ b, float* __restrict__ out){
    int n = (blockIdx.x * blockDim.x + threadIdx.x) >> 6;
    int lane = threadIdx.x & 63;
    if (n >= N_NODES) return;
    float xv = (lane < NF) ? x[n * NF + lane] : 0.f;
    float acc = b[lane];
    #pragma unroll
    for (int d = 0; d < NF; ++d){
        float xd = __shfl(xv, d);
        acc += xd * w[d * DIM + lane];
    }
    out[n * DIM + lane] = fmaxf(acc, 0.f);
}

// merged weight prep: w2T (bf16), LSTM transposes (fp32), GRU hi/lo splits (bf16)
__global__ __launch_bounds__(256) void k_prep(const float* __restrict__ w2,
        const float* __restrict__ lwih, const float* __restrict__ lwhh,
        const float* __restrict__ root, const float* __restrict__ gwih, const float* __restrict__ gwhh,
        u16* __restrict__ w2T, float* __restrict__ wihT, float* __restrict__ whhT,
        u16* __restrict__ rtHi, u16* __restrict__ rtLo,
        u16* __restrict__ wihHi, u16* __restrict__ wihLo,
        u16* __restrict__ whhHi, u16* __restrict__ whhLo){
    int i = blockIdx.x * 256 + threadIdx.x;
    if (i < 524288){
        int k = i >> 12, c = i & 4095;
        w2T[c * HIDN + k] = f2b(w2[i]);
    } else if (i < 557056){
        int i2 = i - 524288;
        int j = i2 >> 7, d = i2 & 127;
        wihT[d * 256 + j] = lwih[i2];
    } else if (i < 573440){
        int i2 = i - 557056;
        int j = i2 >> 6, d = i2 & 63;
        whhT[d * 256 + j] = lwhh[i2];
    } else if (i < 577536){
        int i2 = i - 573440;
        int d = i2 >> 6, j = i2 & 63;
        float v = root[i2]; u16 h = f2b(v);
        rtHi[j * 64 + d] = h; rtLo[j * 64 + d] = f2b(v - b2f(h));
    } else if (i < 589824){
        int k = i - 577536;
        float v = gwih[k]; u16 h = f2b(v);
        wihHi[k] = h; wihLo[k] = f2b(v - b2f(h));
    } else if (i < 602112){
        int k = i - 589824;
        float v = gwhh[k]; u16 h = f2b(v);
        whhHi[k] = h; whhLo[k] = f2b(v - b2f(h));
    }
}

__global__ __launch_bounds__(256) void k_deg(const int* __restrict__ ei, unsigned* __restrict__ degu){
    int e = blockIdx.x * blockDim.x + threadIdx.x;
    if (e < N_EDGES) atomicAdd(&degu[ei[N_EDGES + e]], 1u);
}
__global__ __launch_bounds__(256) void k_dinv(const unsigned* __restrict__ degu, float* __restrict__ dinv){
    int n = blockIdx.x * blockDim.x + threadIdx.x;
    if (n < N_NODES) dinv[n] = 1.f / fmaxf((float)degu[n], 1.f);
}

// ---------------------------------------------------------------------------
// Fused message kernel. EB=64 edges / 256 threads (4 waves). t-fragments
// computed in registers (no s_t LDS). s_b double-buffered -> 1 barrier/iter.
// ---------------------------------------------------------------------------
#define EB   64
#define LDO  68

__global__ __launch_bounds__(256) void k_msg_fused(
        const int* __restrict__ ei, const float* __restrict__ ea,
        const float* __restrict__ w1, const float* __restrict__ b1,
        const u16* __restrict__ w2T, const float* __restrict__ b2,
        const float* __restrict__ out, float* __restrict__ agg)
{
    __shared__ float s_out[EB * LDO];      // 17408 B
    __shared__ u16   s_b[2][64 * 128];     // 32768 B
    __shared__ float s_w1[512];
    __shared__ float s_b1[128];
    int tid = threadIdx.x;
    int e0 = blockIdx.x * EB;

    s_w1[tid] = w1[tid];
    s_w1[tid + 256] = w1[tid + 256];
    if (tid < 128) s_b1[tid] = b1[tid];
    {
        int row = tid >> 2, cb = (tid & 3) * 16;
        int s = ei[e0 + row];
        const float4* sp = (const float4*)(out + (size_t)s * DIM + cb);
        float4 v0 = sp[0], v1 = sp[1], v2 = sp[2], v3 = sp[3];
        float* dst = s_out + row * LDO + cb;
        *(float4*)(dst)      = v0;
        *(float4*)(dst + 4)  = v1;
        *(float4*)(dst + 8)  = v2;
        *(float4*)(dst + 12) = v3;
    }
    __syncthreads();

    int wv = tid >> 6, lane = tid & 63;
    int WR = (wv >> 1) * 32, WC = (wv & 1) * 32;
    int lr = lane & 15, lk = (lane >> 4) * 8;

    // t A-fragments in registers: t[e,h] = relu(b1[h] + ea[e]·w1[:,h]), bf16
    bf16x8 afr[2][4];
    #pragma unroll
    for (int m = 0; m < 2; ++m){
        int erow = e0 + WR + m*16 + lr;
        float4 av = *(const float4*)(ea + (size_t)erow * 4);
        #pragma unroll
        for (int kk = 0; kk < 4; ++kk){
            bf16x8 t8;
            #pragma unroll
            for (int i = 0; i < 8; ++i){
                int h = kk*32 + lk + i;
                float acc = s_b1[h] + av.x*s_w1[h] + av.y*s_w1[128+h]
                          + av.z*s_w1[256+h] + av.w*s_w1[384+h];
                t8[i] = (short)f2b(fmaxf(acc, 0.f));
            }
            afr[m][kk] = t8;
        }
    }

    // B staging: thread (bc=col 0..63, bs=quarter), 4 x 16B per thread
    int bc = tid >> 2, bs = tid & 3;
    const u32x4* gb = (const u32x4*)w2T;
    u32x4 rg[4];
    #pragma unroll
    for (int q = 0; q < 4; ++q) rg[q] = gb[((size_t)bc << 4) + bs*4 + q];

    f32x4 msg[2][2] = {};
    int swzr = (lr & 7) << 4;
    int swzw = (bc & 7) << 4;
    int crow = (lane >> 4) * 4;

    for (int d = 0; d < 64; ++d){
        char* sw = (char*)s_b[d & 1];
        #pragma unroll
        for (int q = 0; q < 4; ++q)
            *(u32x4*)(sw + ((bc*256 + (bs*4+q)*16) ^ swzw)) = rg[q];
        if (d < 63){
            #pragma unroll
            for (int q = 0; q < 4; ++q)
                rg[q] = gb[(((size_t)(d+1)*64 + bc) << 4) + bs*4 + q];
        }
        __syncthreads();
        const char* sr = (const char*)s_b[d & 1];
        f32x4 ew[2][2] = {};
        #pragma unroll
        for (int kk = 0; kk < 4; ++kk){
            int kb = kk*64 + (lane >> 4) * 16;
            bf16x8 bf0 = *(const bf16x8*)(sr + (((WC + lr)*256 + kb)      ^ swzr));
            bf16x8 bf1 = *(const bf16x8*)(sr + (((WC + 16 + lr)*256 + kb) ^ swzr));
            ew[0][0] = __builtin_amdgcn_mfma_f32_16x16x32_bf16(afr[0][kk], bf0, ew[0][0], 0, 0, 0);
            ew[0][1] = __builtin_amdgcn_mfma_f32_16x16x32_bf16(afr[0][kk], bf1, ew[0][1], 0, 0, 0);
            ew[1][0] = __builtin_amdgcn_mfma_f32_16x16x32_bf16(afr[1][kk], bf0, ew[1][0], 0, 0, 0);
            ew[1][1] = __builtin_amdgcn_mfma_f32_16x16x32_bf16(afr[1][kk], bf1, ew[1][1], 0, 0, 0);
        }
        int f0 = d*64 + WC + lr;
        float b2v0 = b2[f0], b2v1 = b2[f0 + 16];
        #pragma unroll
        for (int m = 0; m < 2; ++m){
            #pragma unroll
            for (int r = 0; r < 4; ++r){
                float sc = s_out[(WR + m*16 + crow + r) * LDO + d];
                msg[m][0][r] += sc * (ew[m][0][r] + b2v0);
                msg[m][1][r] += sc * (ew[m][1][r] + b2v1);
            }
        }
    }

    #pragma unroll
    for (int m = 0; m < 2; ++m){
        #pragma unroll
        for (int r = 0; r < 4; ++r){
            int eg = e0 + WR + m*16 + crow + r;
            int dn = ei[N_EDGES + eg];
            atomicAdd(&agg[(size_t)dn * DIM + WC + lr],      msg[m][0][r]);
            atomicAdd(&agg[(size_t)dn * DIM + WC + 16 + lr], msg[m][1][r]);
        }
    }
}

// ---------------------------------------------------------------------------
// k_update: MFMA with bf16x2 (hi+lo) precision splitting (unchanged, passing).
// ---------------------------------------------------------------------------
#define LDH 68
__global__ __launch_bounds__(256) void k_update(
        const u16* __restrict__ rtHi, const u16* __restrict__ rtLo,
        const u16* __restrict__ wihHi, const u16* __restrict__ wihLo,
        const u16* __restrict__ whhHi, const u16* __restrict__ whhLo,
        const float* __restrict__ convb, const float* __restrict__ bih,
        const float* __restrict__ bhh,
        const float* __restrict__ agg, const float* __restrict__ dinv,
        float* __restrict__ out)
{
    __shared__ float s_h[64 * LDH];
    __shared__ float s_aux[64 * LDH];
    __shared__ float s_m[64 * LDH];
    int tid = threadIdx.x;
    int n0 = blockIdx.x * 64;

    {
        int row = tid >> 2, cb = (tid & 3) * 16;
        const float4* hp = (const float4*)(out + (size_t)(n0 + row) * DIM + cb);
        const float4* ap = (const float4*)(agg + (size_t)(n0 + row) * DIM + cb);
        float di = dinv[n0 + row];
        #pragma unroll
        for (int q = 0; q < 4; ++q){
            float4 hv = hp[q];
            float4 av = ap[q];
            *(float4*)(s_h + row * LDH + cb + q*4) = hv;
            float4 xv;
            xv.x = av.x * di + convb[cb + q*4 + 0];
            xv.y = av.y * di + convb[cb + q*4 + 1];
            xv.z = av.z * di + convb[cb + q*4 + 2];
            xv.w = av.w * di + convb[cb + q*4 + 3];
            *(float4*)(s_aux + row * LDH + cb + q*4) = xv;
        }
    }
    __syncthreads();

    int wv = tid >> 6, lane = tid & 63;
    int lr = lane & 15, lkb = (lane >> 4) * 8;
    int arow = wv * 16 + lr;

    bf16x8 hHi[2], hLo[2];
    #pragma unroll
    for (int kk = 0; kk < 2; ++kk){
        const float* src = s_h + arow * LDH + kk*32 + lkb;
        bf16x8 hi8, lo8;
        #pragma unroll
        for (int e = 0; e < 8; ++e){
            float v = src[e];
            u16 h = f2b(v);
            hi8[e] = (short)h;
            lo8[e] = (short)f2b(v - b2f(h));
        }
        hHi[kk] = hi8; hLo[kk] = lo8;
    }

    f32x4 c1[4] = {};
    #pragma unroll
    for (int ct = 0; ct < 4; ++ct){
        #pragma unroll
        for (int kk = 0; kk < 2; ++kk){
            int off = (ct*16 + lr) * 64 + kk*32 + lkb;
            bf16x8 bHi = *(const bf16x8*)(rtHi + off);
            bf16x8 bLo = *(const bf16x8*)(rtLo + off);
            c1[ct] = __builtin_amdgcn_mfma_f32_16x16x32_bf16(hHi[kk], bHi, c1[ct], 0, 0, 0);
            c1[ct] = __builtin_amdgcn_mfma_f32_16x16x32_bf16(hLo[kk], bHi, c1[ct], 0, 0, 0);
            c1[ct] = __builtin_amdgcn_mfma_f32_16x16x32_bf16(hHi[kk], bLo, c1[ct], 0, 0, 0);
        }
    }

    int crow = (lane >> 4) * 4;
    #pragma unroll
    for (int ct = 0; ct < 4; ++ct){
        #pragma unroll
        for (int r = 0; r < 4; ++r){
            int row = wv*16 + crow + r;
            int col = ct*16 + lr;
            float m = fmaxf(c1[ct][r] + s_aux[row * LDH + col], 0.f);
            s_m[row * LDH + col] = m;
        }
    }
    __syncthreads();

    bf16x8 mHi[2], mLo[2];
    #pragma unroll
    for (int kk = 0; kk < 2; ++kk){
        const float* src = s_m + arow * LDH + kk*32 + lkb;
        bf16x8 hi8, lo8;
        #pragma unroll
        for (int e = 0; e < 8; ++e){
            float v = src[e];
            u16 h = f2b(v);
            hi8[e] = (short)h;
            lo8[e] = (short)f2b(v - b2f(h));
        }
        mHi[kk] = hi8; mLo[kk] = lo8;
    }

    f32x4 gi[12] = {}, gh[12] = {};
    #pragma unroll
    for (int ct = 0; ct < 12; ++ct){
        #pragma unroll
        for (int kk = 0; kk < 2; ++kk){
            int off = (ct*16 + lr) * 64 + kk*32 + lkb;
            bf16x8 biH = *(const bf16x8*)(wihHi + off);
            bf16x8 biL = *(const bf16x8*)(wihLo + off);
            gi[ct] = __builtin_amdgcn_mfma_f32_16x16x32_bf16(mHi[kk], biH, gi[ct], 0, 0, 0);
            gi[ct] = __builtin_amdgcn_mfma_f32_16x16x32_bf16(mLo[kk], biH, gi[ct], 0, 0, 0);
            gi[ct] = __builtin_amdgcn_mfma_f32_16x16x32_bf16(mHi[kk], biL, gi[ct], 0, 0, 0);
            bf16x8 bhH = *(const bf16x8*)(whhHi + off);
            bf16x8 bhL = *(const bf16x8*)(whhLo + off);
            gh[ct] = __builtin_amdgcn_mfma_f32_16x16x32_bf16(hHi[kk], bhH, gh[ct], 0, 0, 0);
            gh[ct] = __builtin_amdgcn_mfma_f32_16x16x32_bf16(hLo[kk], bhH, gh[ct], 0, 0, 0);
            gh[ct] = __builtin_amdgcn_mfma_f32_16x16x32_bf16(hHi[kk], bhL, gh[ct], 0, 0, 0);
        }
    }

    #pragma unroll
    for (int ct = 0; ct < 4; ++ct){
        int col = ct*16 + lr;
        float br_i = bih[col],       br_h = bhh[col];
        float bz_i = bih[64 + col],  bz_h = bhh[64 + col];
        float bn_i = bih[128 + col], bn_h = bhh[128 + col];
        #pragma unroll
        for (int r = 0; r < 4; ++r){
            int row = wv*16 + crow + r;
            float rg = sigf(gi[ct][r] + br_i + gh[ct][r] + br_h);
            float zg = sigf(gi[ct+4][r] + bz_i + gh[ct+4][r] + bz_h);
            float ng = tanhf(gi[ct+8][r] + bn_i + rg * (gh[ct+8][r] + bn_h));
            float h  = s_h[row * LDH + col];
            s_aux[row * LDH + col] = (1.f - zg) * ng + zg * h;
        }
    }
    __syncthreads();

    {
        int row = tid >> 2, cb = (tid & 3) * 16;
        #pragma unroll
        for (int q = 0; q < 4; ++q)
            *(float4*)(out + (size_t)(n0 + row) * DIM + cb + q*4) =
                *(const float4*)(s_aux + row * LDH + cb + q*4);
    }
}

// ---------------------------------------------------------------------------
// Fully fused Set2Set (3 steps) + final MLP. One block per graph (batch is
// sorted -> node range via binary search). Replaces 19 dispatches.
// ---------------------------------------------------------------------------
__global__ __launch_bounds__(256) void k_s2s(
        const float* __restrict__ out, const int* __restrict__ batch,
        const float* __restrict__ wihT, const float* __restrict__ lbih,
        const float* __restrict__ whhT, const float* __restrict__ lbhh,
        const float* __restrict__ l1w, const float* __restrict__ l1b,
        const float* __restrict__ l2w, const float* __restrict__ l2b,
        float* __restrict__ ebuf, float* __restrict__ y)
{
    __shared__ float s_q[128];     // q_star
    __shared__ float s_hc[128];    // h (0..63), c (64..127)
    __shared__ float s_g[256];
    __shared__ float s_rw[256];
    __shared__ float s_sw[8];
    __shared__ int   s_rng[2];
    int g = blockIdx.x, tid = threadIdx.x;
    if (tid < 2){
        int target = g + tid;
        int lo = 0, hi = N_NODES;
        while (lo < hi){ int mid = (lo + hi) >> 1; if (batch[mid] < target) lo = mid + 1; else hi = mid; }
        s_rng[tid] = lo;
    }
    if (tid < 128){ s_q[tid] = 0.f; s_hc[tid] = 0.f; }
    __syncthreads();
    int s0 = s_rng[0], s1 = s_rng[1];
    int wv = tid >> 6, lane = tid & 63;

    for (int step = 0; step < 3; ++step){
        // LSTM gates: j = tid
        float acc = lbih[tid] + lbhh[tid];
        #pragma unroll 8
        for (int d = 0; d < 128; ++d) acc += s_q[d] * wihT[d * 256 + tid];
        #pragma unroll 8
        for (int d = 0; d < 64;  ++d) acc += s_hc[d] * whhT[d * 256 + tid];
        s_g[tid] = acc;
        __syncthreads();
        if (tid < 64){
            float c = sigf(s_g[64 + tid]) * s_hc[64 + tid] + sigf(s_g[tid]) * tanhf(s_g[128 + tid]);
            float h = sigf(s_g[192 + tid]) * tanhf(c);
            s_hc[tid] = h; s_hc[64 + tid] = c;
            s_q[tid] = h;                        // q part of q_star
        }
        __syncthreads();
        // attention pass 1: e_n = <out[n], q>, track max
        float q = s_hc[lane];
        float emx = -3.4e38f;
        for (int n = s0 + wv; n < s1; n += 4){
            float v = out[(size_t)n * DIM + lane] * q;
            #pragma unroll
            for (int off = 32; off; off >>= 1) v += __shfl_xor(v, off);
            if (lane == 0) ebuf[n] = v;
            emx = fmaxf(emx, v);
        }
        if (lane == 0) s_sw[wv] = emx;
        __syncthreads();
        float gmax = fmaxf(fmaxf(s_sw[0], s_sw[1]), fmaxf(s_sw[2], s_sw[3]));
        // pass 2: softmax-weighted sum
        float rl = 0.f, ss = 0.f;
        for (int n = s0 + wv; n < s1; n += 4){
            float ex = expf(ebuf[n] - gmax);
            rl += ex * out[(size_t)n * DIM + lane];
            ss += ex;
        }
        s_rw[wv * 64 + lane] = rl;
        if (lane == 0) s_sw[4 + wv] = ss;
        __syncthreads();
        if (tid < 64){
            float r = s_rw[tid] + s_rw[64 + tid] + s_rw[128 + tid] + s_rw[192 + tid];
            float S = fmaxf(s_sw[4] + s_sw[5] + s_sw[6] + s_sw[7], 1e-16f);
            s_q[64 + tid] = r / S;
        }
        __syncthreads();
    }
    if (wv == 0){
        float acc = l1b[lane];
        #pragma unroll 8
        for (int d = 0; d < 128; ++d) acc += s_q[d] * l1w[d * 64 + lane];
        float h = fmaxf(acc, 0.f);
        float p = h * l2w[lane];
        #pragma unroll
        for (int off = 32; off; off >>= 1) p += __shfl_down(p, off);
        if (lane == 0) y[g] = p + l2b[0];
    }
}

extern "C" void kernel_launch(void* const* d_in, const int* in_sizes, int n_in,
                              void* d_out, int out_size, void* d_ws, size_t ws_size,
                              hipStream_t stream){
    const float* x      = (const float*)d_in[0];
    const int*   ei     = (const int*)d_in[1];
    const float* ea     = (const float*)d_in[2];
    const int*   batch  = (const int*)d_in[3];
    const float* lin0_w = (const float*)d_in[6];
    const float* lin0_b = (const float*)d_in[7];
    const float* nn1_w  = (const float*)d_in[8];
    const float* nn1_b  = (const float*)d_in[9];
    const float* nn2_w  = (const float*)d_in[10];
    const float* nn2_b  = (const float*)d_in[11];
    const float* root_w = (const float*)d_in[12];
    const float* conv_b = (const float*)d_in[13];
    const float* gwih   = (const float*)d_in[14];
    const float* gwhh   = (const float*)d_in[15];
    const float* gbih   = (const float*)d_in[16];
    const float* gbhh   = (const float*)d_in[17];
    const float* lwih   = (const float*)d_in[18];
    const float* lwhh   = (const float*)d_in[19];
    const float* lbih   = (const float*)d_in[20];
    const float* lbhh   = (const float*)d_in[21];
    const float* l1w    = (const float*)d_in[22];
    const float* l1b    = (const float*)d_in[23];
    const float* l2w    = (const float*)d_in[24];
    const float* l2b    = (const float*)d_in[25];
    float* y = (float*)d_out;

    char* p = (char*)d_ws;
    float* out   = (float*)p;    p += (size_t)N_NODES * DIM * 4;
    float* agg   = (float*)p;    p += (size_t)N_NODES * DIM * 4;
    u16* w2T     = (u16*)p;      p += (size_t)EWCOLS * HIDN * 2;
    float* wihT  = (float*)p;    p += 128 * 256 * 4;
    float* whhT  = (float*)p;    p += 64 * 256 * 4;
    u16* rtHi    = (u16*)p;      p += 4096 * 2;
    u16* rtLo    = (u16*)p;      p += 4096 * 2;
    u16* wihHi   = (u16*)p;      p += 12288 * 2;
    u16* wihLo   = (u16*)p;      p += 12288 * 2;
    u16* whhHi   = (u16*)p;      p += 12288 * 2;
    u16* whhLo   = (u16*)p;      p += 12288 * 2;
    unsigned* degu = (unsigned*)p; p += N_NODES * 4;
    float* dinv  = (float*)p;    p += N_NODES * 4;
    float* ebuf  = (float*)p;    p += N_NODES * 4;

    if ((size_t)(p - (char*)d_ws) > ws_size) return;

    hipMemsetAsync(degu, 0, N_NODES * 4, stream);

    k_prep<<<2352, 256, 0, stream>>>(nn2_w, lwih, lwhh, root_w, gwih, gwhh,
                w2T, wihT, whhT, rtHi, rtLo, wihHi, wihLo, whhHi, whhLo);
    k_lin0<<<N_NODES / 4, 256, 0, stream>>>(x, lin0_w, lin0_b, out);
    k_deg <<<N_EDGES / 256, 256, 0, stream>>>(ei, degu);
    k_dinv<<<N_NODES / 256, 256, 0, stream>>>(degu, dinv);

    for (int r = 0; r < 3; ++r){
        hipMemsetAsync(agg, 0, (size_t)N_NODES * DIM * 4, stream);
        k_msg_fused<<<N_EDGES / EB, 256, 0, stream>>>(ei, ea, nn1_w, nn1_b, w2T, nn2_b, out, agg);
        k_update   <<<N_NODES / 64, 256, 0, stream>>>(rtHi, rtLo, wihHi, wihLo, whhHi, whhLo,
                        conv_b, gbih, gbhh, agg, dinv, out);
    }

    k_s2s<<<NGRAPH, 256, 0, stream>>>(out, batch, wihT, lbih, whhT, lbhh,
                l1w, l1b, l2w, l2b, ebuf, y);
}

// Round 5
// 300.916 us; speedup vs baseline: 5.6080x; 1.2297x over previous
//
#include <hip/hip_runtime.h>
#include <math.h>

#define N_NODES 16384
#define N_EDGES 32768
#define NGRAPH  512
#define DIM     64
#define NF      14
#define HIDN    128
#define EWCOLS  4096

typedef unsigned short u16;
typedef unsigned int   u32;
typedef __attribute__((ext_vector_type(8))) short bf16x8;
typedef __attribute__((ext_vector_type(4))) float f32x4;
typedef __attribute__((ext_vector_type(4))) u32   u32x4;

__device__ inline float b2f(u16 u){
    unsigned int x = ((unsigned int)u) << 16;
    return __builtin_bit_cast(float, x);
}
__device__ inline u16 f2b(float f){
    unsigned int x = __builtin_bit_cast(unsigned int, f);
    unsigned int r = (x + 0x7FFFu + ((x >> 16) & 1u)) >> 16;   // RNE
    return (u16)r;
}
__device__ inline float sigf(float x){ return 1.f / (1.f + expf(-x)); }

// out[n,f] = relu(x[n,:14] @ lin0_w + lin0_b)
__global__ __launch_bounds__(256) void k_lin0(const float* __restrict__ x,
        const float* __restrict__ w, const float* __restrict__ b, float* __restrict__ out){
    int n = (blockIdx.x * blockDim.x + threadIdx.x) >> 6;
    int lane = threadIdx.x & 63;
    if (n >= N_NODES) return;
    float xv = (lane < NF) ? x[n * NF + lane] : 0.f;
    float acc = b[lane];
    #pragma unroll
    for (int d = 0; d < NF; ++d){
        float xd = __shfl(xv, d);
        acc += xd * w[d * DIM + lane];
    }
    out[n * DIM + lane] = fmaxf(acc, 0.f);
}

// merged weight prep: w2T (bf16), LSTM transposes (fp32), GRU hi/lo splits (bf16)
__global__ __launch_bounds__(256) void k_prep(const float* __restrict__ w2,
        const float* __restrict__ lwih, const float* __restrict__ lwhh,
        const float* __restrict__ root, const float* __restrict__ gwih, const float* __restrict__ gwhh,
        u16* __restrict__ w2T, float* __restrict__ wihT, float* __restrict__ whhT,
        u16* __restrict__ rtHi, u16* __restrict__ rtLo,
        u16* __restrict__ wihHi, u16* __restrict__ wihLo,
        u16* __restrict__ whhHi, u16* __restrict__ whhLo){
    int i = blockIdx.x * 256 + threadIdx.x;
    if (i < 524288){
        int k = i >> 12, c = i & 4095;
        w2T[c * HIDN + k] = f2b(w2[i]);
    } else if (i < 557056){
        int i2 = i - 524288;
        int j = i2 >> 7, d = i2 & 127;
        wihT[d * 256 + j] = lwih[i2];
    } else if (i < 573440){
        int i2 = i - 557056;
        int j = i2 >> 6, d = i2 & 63;
        whhT[d * 256 + j] = lwhh[i2];
    } else if (i < 577536){
        int i2 = i - 573440;
        int d = i2 >> 6, j = i2 & 63;
        float v = root[i2]; u16 h = f2b(v);
        rtHi[j * 64 + d] = h; rtLo[j * 64 + d] = f2b(v - b2f(h));
    } else if (i < 589824){
        int k = i - 577536;
        float v = gwih[k]; u16 h = f2b(v);
        wihHi[k] = h; wihLo[k] = f2b(v - b2f(h));
    } else if (i < 602112){
        int k = i - 589824;
        float v = gwhh[k]; u16 h = f2b(v);
        whhHi[k] = h; whhLo[k] = f2b(v - b2f(h));
    }
}

__global__ __launch_bounds__(256) void k_deg(const int* __restrict__ ei, unsigned* __restrict__ degu){
    int e = blockIdx.x * blockDim.x + threadIdx.x;
    if (e < N_EDGES) atomicAdd(&degu[ei[N_EDGES + e]], 1u);
}
__global__ __launch_bounds__(256) void k_dinv(const unsigned* __restrict__ degu, float* __restrict__ dinv){
    int n = blockIdx.x * blockDim.x + threadIdx.x;
    if (n < N_NODES) dinv[n] = 1.f / fmaxf((float)degu[n], 1.f);
}

// ---------------------------------------------------------------------------
// Fused message kernel. EB=128 edges / 512 threads (8 waves).
// t-fragments in registers; s_b double-buffered (1 barrier/iter); b2 in LDS.
// ---------------------------------------------------------------------------
#define EB   128
#define LDO  68

__global__ __launch_bounds__(512) void k_msg_fused(
        const int* __restrict__ ei, const float* __restrict__ ea,
        const float* __restrict__ w1, const float* __restrict__ b1,
        const u16* __restrict__ w2T, const float* __restrict__ b2,
        const float* __restrict__ out, float* __restrict__ agg)
{
    __shared__ float s_out[EB * LDO];      // 34816 B
    __shared__ u16   s_b[2][64 * 128];     // 32768 B
    __shared__ float s_b2[EWCOLS];         // 16384 B
    __shared__ float s_w1[512];
    __shared__ float s_b1[128];
    int tid = threadIdx.x;
    int e0 = blockIdx.x * EB;

    s_w1[tid] = w1[tid];
    if (tid < 128) s_b1[tid] = b1[tid];
    {
        int base = tid * 8;
        *(float4*)(s_b2 + base)     = *(const float4*)(b2 + base);
        *(float4*)(s_b2 + base + 4) = *(const float4*)(b2 + base + 4);
    }
    {
        int row = tid >> 2, cb = (tid & 3) * 16;
        int s = ei[e0 + row];
        const float4* sp = (const float4*)(out + (size_t)s * DIM + cb);
        float4 v0 = sp[0], v1 = sp[1], v2 = sp[2], v3 = sp[3];
        float* dst = s_out + row * LDO + cb;
        *(float4*)(dst)      = v0;
        *(float4*)(dst + 4)  = v1;
        *(float4*)(dst + 8)  = v2;
        *(float4*)(dst + 12) = v3;
    }
    __syncthreads();

    int wv = tid >> 6, lane = tid & 63;
    int WR = (wv >> 1) * 32, WC = (wv & 1) * 32;
    int lr = lane & 15, lk = (lane >> 4) * 8;

    // t A-fragments in registers: t[e,h] = relu(b1[h] + ea[e]·w1[:,h]), bf16
    bf16x8 afr[2][4];
    #pragma unroll
    for (int m = 0; m < 2; ++m){
        int erow = e0 + WR + m*16 + lr;
        float4 av = *(const float4*)(ea + (size_t)erow * 4);
        #pragma unroll
        for (int kk = 0; kk < 4; ++kk){
            bf16x8 t8;
            #pragma unroll
            for (int i = 0; i < 8; ++i){
                int h = kk*32 + lk + i;
                float acc = s_b1[h] + av.x*s_w1[h] + av.y*s_w1[128+h]
                          + av.z*s_w1[256+h] + av.w*s_w1[384+h];
                t8[i] = (short)f2b(fmaxf(acc, 0.f));
            }
            afr[m][kk] = t8;
        }
    }

    // B staging: thread (bc=col 0..63, bs=eighth of 256B row), 2 x 16B
    int bc = tid >> 3, bs = tid & 7;
    const u32x4* gb = (const u32x4*)w2T;
    u32x4 r0 = gb[((size_t)bc << 4) + bs*2];
    u32x4 r1 = gb[((size_t)bc << 4) + bs*2 + 1];

    f32x4 msg[2][2] = {};
    int swzr = (lr & 7) << 4;
    int swzw = (bc & 7) << 4;
    int crow = (lane >> 4) * 4;

    for (int d = 0; d < 64; ++d){
        char* sw = (char*)s_b[d & 1];
        *(u32x4*)(sw + ((bc*256 + bs*32)      ^ swzw)) = r0;
        *(u32x4*)(sw + ((bc*256 + bs*32 + 16) ^ swzw)) = r1;
        if (d < 63){
            size_t base = ((size_t)(d+1)*64 + bc) << 4;
            r0 = gb[base + bs*2];
            r1 = gb[base + bs*2 + 1];
        }
        __syncthreads();
        const char* sr = (const char*)s_b[d & 1];
        f32x4 ew[2][2] = {};
        #pragma unroll
        for (int kk = 0; kk < 4; ++kk){
            int kb = kk*64 + (lane >> 4) * 16;
            bf16x8 bf0 = *(const bf16x8*)(sr + (((WC + lr)*256 + kb)      ^ swzr));
            bf16x8 bf1 = *(const bf16x8*)(sr + (((WC + 16 + lr)*256 + kb) ^ swzr));
            ew[0][0] = __builtin_amdgcn_mfma_f32_16x16x32_bf16(afr[0][kk], bf0, ew[0][0], 0, 0, 0);
            ew[0][1] = __builtin_amdgcn_mfma_f32_16x16x32_bf16(afr[0][kk], bf1, ew[0][1], 0, 0, 0);
            ew[1][0] = __builtin_amdgcn_mfma_f32_16x16x32_bf16(afr[1][kk], bf0, ew[1][0], 0, 0, 0);
            ew[1][1] = __builtin_amdgcn_mfma_f32_16x16x32_bf16(afr[1][kk], bf1, ew[1][1], 0, 0, 0);
        }
        float b2v0 = s_b2[d*64 + WC + lr];
        float b2v1 = s_b2[d*64 + WC + 16 + lr];
        #pragma unroll
        for (int m = 0; m < 2; ++m){
            #pragma unroll
            for (int r = 0; r < 4; ++r){
                float sc = s_out[(WR + m*16 + crow + r) * LDO + d];
                msg[m][0][r] += sc * (ew[m][0][r] + b2v0);
                msg[m][1][r] += sc * (ew[m][1][r] + b2v1);
            }
        }
    }

    #pragma unroll
    for (int m = 0; m < 2; ++m){
        #pragma unroll
        for (int r = 0; r < 4; ++r){
            int eg = e0 + WR + m*16 + crow + r;
            int dn = ei[N_EDGES + eg];
            atomicAdd(&agg[(size_t)dn * DIM + WC + lr],      msg[m][0][r]);
            atomicAdd(&agg[(size_t)dn * DIM + WC + 16 + lr], msg[m][1][r]);
        }
    }
}

// ---------------------------------------------------------------------------
// k_update: MFMA with bf16x2 (hi+lo) precision splitting (unchanged, passing).
// ---------------------------------------------------------------------------
#define LDH 68
__global__ __launch_bounds__(256) void k_update(
        const u16* __restrict__ rtHi, const u16* __restrict__ rtLo,
        const u16* __restrict__ wihHi, const u16* __restrict__ wihLo,
        const u16* __restrict__ whhHi, const u16* __restrict__ whhLo,
        const float* __restrict__ convb, const float* __restrict__ bih,
        const float* __restrict__ bhh,
        const float* __restrict__ agg, const float* __restrict__ dinv,
        float* __restrict__ out)
{
    __shared__ float s_h[64 * LDH];
    __shared__ float s_aux[64 * LDH];
    __shared__ float s_m[64 * LDH];
    int tid = threadIdx.x;
    int n0 = blockIdx.x * 64;

    {
        int row = tid >> 2, cb = (tid & 3) * 16;
        const float4* hp = (const float4*)(out + (size_t)(n0 + row) * DIM + cb);
        const float4* ap = (const float4*)(agg + (size_t)(n0 + row) * DIM + cb);
        float di = dinv[n0 + row];
        #pragma unroll
        for (int q = 0; q < 4; ++q){
            float4 hv = hp[q];
            float4 av = ap[q];
            *(float4*)(s_h + row * LDH + cb + q*4) = hv;
            float4 xv;
            xv.x = av.x * di + convb[cb + q*4 + 0];
            xv.y = av.y * di + convb[cb + q*4 + 1];
            xv.z = av.z * di + convb[cb + q*4 + 2];
            xv.w = av.w * di + convb[cb + q*4 + 3];
            *(float4*)(s_aux + row * LDH + cb + q*4) = xv;
        }
    }
    __syncthreads();

    int wv = tid >> 6, lane = tid & 63;
    int lr = lane & 15, lkb = (lane >> 4) * 8;
    int arow = wv * 16 + lr;

    bf16x8 hHi[2], hLo[2];
    #pragma unroll
    for (int kk = 0; kk < 2; ++kk){
        const float* src = s_h + arow * LDH + kk*32 + lkb;
        bf16x8 hi8, lo8;
        #pragma unroll
        for (int e = 0; e < 8; ++e){
            float v = src[e];
            u16 h = f2b(v);
            hi8[e] = (short)h;
            lo8[e] = (short)f2b(v - b2f(h));
        }
        hHi[kk] = hi8; hLo[kk] = lo8;
    }

    f32x4 c1[4] = {};
    #pragma unroll
    for (int ct = 0; ct < 4; ++ct){
        #pragma unroll
        for (int kk = 0; kk < 2; ++kk){
            int off = (ct*16 + lr) * 64 + kk*32 + lkb;
            bf16x8 bHi = *(const bf16x8*)(rtHi + off);
            bf16x8 bLo = *(const bf16x8*)(rtLo + off);
            c1[ct] = __builtin_amdgcn_mfma_f32_16x16x32_bf16(hHi[kk], bHi, c1[ct], 0, 0, 0);
            c1[ct] = __builtin_amdgcn_mfma_f32_16x16x32_bf16(hLo[kk], bHi, c1[ct], 0, 0, 0);
            c1[ct] = __builtin_amdgcn_mfma_f32_16x16x32_bf16(hHi[kk], bLo, c1[ct], 0, 0, 0);
        }
    }

    int crow = (lane >> 4) * 4;
    #pragma unroll
    for (int ct = 0; ct < 4; ++ct){
        #pragma unroll
        for (int r = 0; r < 4; ++r){
            int row = wv*16 + crow + r;
            int col = ct*16 + lr;
            float m = fmaxf(c1[ct][r] + s_aux[row * LDH + col], 0.f);
            s_m[row * LDH + col] = m;
        }
    }
    __syncthreads();

    bf16x8 mHi[2], mLo[2];
    #pragma unroll
    for (int kk = 0; kk < 2; ++kk){
        const float* src = s_m + arow * LDH + kk*32 + lkb;
        bf16x8 hi8, lo8;
        #pragma unroll
        for (int e = 0; e < 8; ++e){
            float v = src[e];
            u16 h = f2b(v);
            hi8[e] = (short)h;
            lo8[e] = (short)f2b(v - b2f(h));
        }
        mHi[kk] = hi8; mLo[kk] = lo8;
    }

    f32x4 gi[12] = {}, gh[12] = {};
    #pragma unroll
    for (int ct = 0; ct < 12; ++ct){
        #pragma unroll
        for (int kk = 0; kk < 2; ++kk){
            int off = (ct*16 + lr) * 64 + kk*32 + lkb;
            bf16x8 biH = *(const bf16x8*)(wihHi + off);
            bf16x8 biL = *(const bf16x8*)(wihLo + off);
            gi[ct] = __builtin_amdgcn_mfma_f32_16x16x32_bf16(mHi[kk], biH, gi[ct], 0, 0, 0);
            gi[ct] = __builtin_amdgcn_mfma_f32_16x16x32_bf16(mLo[kk], biH, gi[ct], 0, 0, 0);
            gi[ct] = __builtin_amdgcn_mfma_f32_16x16x32_bf16(mHi[kk], biL, gi[ct], 0, 0, 0);
            bf16x8 bhH = *(const bf16x8*)(whhHi + off);
            bf16x8 bhL = *(const bf16x8*)(whhLo + off);
            gh[ct] = __builtin_amdgcn_mfma_f32_16x16x32_bf16(hHi[kk], bhH, gh[ct], 0, 0, 0);
            gh[ct] = __builtin_amdgcn_mfma_f32_16x16x32_bf16(hLo[kk], bhH, gh[ct], 0, 0, 0);
            gh[ct] = __builtin_amdgcn_mfma_f32_16x16x32_bf16(hHi[kk], bhL, gh[ct], 0, 0, 0);
        }
    }

    #pragma unroll
    for (int ct = 0; ct < 4; ++ct){
        int col = ct*16 + lr;
        float br_i = bih[col],       br_h = bhh[col];
        float bz_i = bih[64 + col],  bz_h = bhh[64 + col];
        float bn_i = bih[128 + col], bn_h = bhh[128 + col];
        #pragma unroll
        for (int r = 0; r < 4; ++r){
            int row = wv*16 + crow + r;
            float rg = sigf(gi[ct][r] + br_i + gh[ct][r] + br_h);
            float zg = sigf(gi[ct+4][r] + bz_i + gh[ct+4][r] + bz_h);
            float ng = tanhf(gi[ct+8][r] + bn_i + rg * (gh[ct+8][r] + bn_h));
            float h  = s_h[row * LDH + col];
            s_aux[row * LDH + col] = (1.f - zg) * ng + zg * h;
        }
    }
    __syncthreads();

    {
        int row = tid >> 2, cb = (tid & 3) * 16;
        #pragma unroll
        for (int q = 0; q < 4; ++q)
            *(float4*)(out + (size_t)(n0 + row) * DIM + cb + q*4) =
                *(const float4*)(s_aux + row * LDH + cb + q*4);
    }
}

// ---------------------------------------------------------------------------
// Fully fused Set2Set (3 steps) + final MLP. One block per graph.
// Scores recomputed in pass 2 (no global ebuf round trip).
// ---------------------------------------------------------------------------
__global__ __launch_bounds__(256) void k_s2s(
        const float* __restrict__ out, const int* __restrict__ batch,
        const float* __restrict__ wihT, const float* __restrict__ lbih,
        const float* __restrict__ whhT, const float* __restrict__ lbhh,
        const float* __restrict__ l1w, const float* __restrict__ l1b,
        const float* __restrict__ l2w, const float* __restrict__ l2b,
        float* __restrict__ y)
{
    __shared__ float s_q[128];     // q_star
    __shared__ float s_hc[128];    // h (0..63), c (64..127)
    __shared__ float s_g[256];
    __shared__ float s_rw[256];
    __shared__ float s_sw[8];
    __shared__ int   s_rng[2];
    int g = blockIdx.x, tid = threadIdx.x;
    if (tid < 2){
        int target = g + tid;
        int lo = 0, hi = N_NODES;
        while (lo < hi){ int mid = (lo + hi) >> 1; if (batch[mid] < target) lo = mid + 1; else hi = mid; }
        s_rng[tid] = lo;
    }
    if (tid < 128){ s_q[tid] = 0.f; s_hc[tid] = 0.f; }
    __syncthreads();
    int s0 = s_rng[0], s1 = s_rng[1];
    int wv = tid >> 6, lane = tid & 63;

    for (int step = 0; step < 3; ++step){
        float acc = lbih[tid] + lbhh[tid];
        #pragma unroll 8
        for (int d = 0; d < 128; ++d) acc += s_q[d] * wihT[d * 256 + tid];
        #pragma unroll 8
        for (int d = 0; d < 64;  ++d) acc += s_hc[d] * whhT[d * 256 + tid];
        s_g[tid] = acc;
        __syncthreads();
        if (tid < 64){
            float c = sigf(s_g[64 + tid]) * s_hc[64 + tid] + sigf(s_g[tid]) * tanhf(s_g[128 + tid]);
            float h = sigf(s_g[192 + tid]) * tanhf(c);
            s_hc[tid] = h; s_hc[64 + tid] = c;
            s_q[tid] = h;
        }
        __syncthreads();
        float q = s_hc[lane];
        float emx = -3.4e38f;
        for (int n = s0 + wv; n < s1; n += 4){
            float v = out[(size_t)n * DIM + lane] * q;
            #pragma unroll
            for (int off = 32; off; off >>= 1) v += __shfl_xor(v, off);
            emx = fmaxf(emx, v);
        }
        if (lane == 0) s_sw[wv] = emx;
        __syncthreads();
        float gmax = fmaxf(fmaxf(s_sw[0], s_sw[1]), fmaxf(s_sw[2], s_sw[3]));
        float rl = 0.f, ss = 0.f;
        for (int n = s0 + wv; n < s1; n += 4){
            float o = out[(size_t)n * DIM + lane];
            float v = o * q;
            #pragma unroll
            for (int off = 32; off; off >>= 1) v += __shfl_xor(v, off);
            float ex = expf(v - gmax);
            rl += ex * o;
            ss += ex;
        }
        s_rw[wv * 64 + lane] = rl;
        if (lane == 0) s_sw[4 + wv] = ss;
        __syncthreads();
        if (tid < 64){
            float r = s_rw[tid] + s_rw[64 + tid] + s_rw[128 + tid] + s_rw[192 + tid];
            float S = fmaxf(s_sw[4] + s_sw[5] + s_sw[6] + s_sw[7], 1e-16f);
            s_q[64 + tid] = r / S;
        }
        __syncthreads();
    }
    if (wv == 0){
        float acc = l1b[lane];
        #pragma unroll 8
        for (int d = 0; d < 128; ++d) acc += s_q[d] * l1w[d * 64 + lane];
        float h = fmaxf(acc, 0.f);
        float p = h * l2w[lane];
        #pragma unroll
        for (int off = 32; off; off >>= 1) p += __shfl_down(p, off);
        if (lane == 0) y[g] = p + l2b[0];
    }
}

extern "C" void kernel_launch(void* const* d_in, const int* in_sizes, int n_in,
                              void* d_out, int out_size, void* d_ws, size_t ws_size,
                              hipStream_t stream){
    const float* x      = (const float*)d_in[0];
    const int*   ei     = (const int*)d_in[1];
    const float* ea     = (const float*)d_in[2];
    const int*   batch  = (const int*)d_in[3];
    const float* lin0_w = (const float*)d_in[6];
    const float* lin0_b = (const float*)d_in[7];
    const float* nn1_w  = (const float*)d_in[8];
    const float* nn1_b  = (const float*)d_in[9];
    const float* nn2_w  = (const float*)d_in[10];
    const float* nn2_b  = (const float*)d_in[11];
    const float* root_w = (const float*)d_in[12];
    const float* conv_b = (const float*)d_in[13];
    const float* gwih   = (const float*)d_in[14];
    const float* gwhh   = (const float*)d_in[15];
    const float* gbih   = (const float*)d_in[16];
    const float* gbhh   = (const float*)d_in[17];
    const float* lwih   = (const float*)d_in[18];
    const float* lwhh   = (const float*)d_in[19];
    const float* lbih   = (const float*)d_in[20];
    const float* lbhh   = (const float*)d_in[21];
    const float* l1w    = (const float*)d_in[22];
    const float* l1b    = (const float*)d_in[23];
    const float* l2w    = (const float*)d_in[24];
    const float* l2b    = (const float*)d_in[25];
    float* y = (float*)d_out;

    char* p = (char*)d_ws;
    float* out   = (float*)p;    p += (size_t)N_NODES * DIM * 4;
    float* agg   = (float*)p;    p += (size_t)N_NODES * DIM * 4;
    u16* w2T     = (u16*)p;      p += (size_t)EWCOLS * HIDN * 2;
    float* wihT  = (float*)p;    p += 128 * 256 * 4;
    float* whhT  = (float*)p;    p += 64 * 256 * 4;
    u16* rtHi    = (u16*)p;      p += 4096 * 2;
    u16* rtLo    = (u16*)p;      p += 4096 * 2;
    u16* wihHi   = (u16*)p;      p += 12288 * 2;
    u16* wihLo   = (u16*)p;      p += 12288 * 2;
    u16* whhHi   = (u16*)p;      p += 12288 * 2;
    u16* whhLo   = (u16*)p;      p += 12288 * 2;
    unsigned* degu = (unsigned*)p; p += N_NODES * 4;
    float* dinv  = (float*)p;    p += N_NODES * 4;

    if ((size_t)(p - (char*)d_ws) > ws_size) return;

    hipMemsetAsync(degu, 0, N_NODES * 4, stream);

    k_prep<<<2352, 256, 0, stream>>>(nn2_w, lwih, lwhh, root_w, gwih, gwhh,
                w2T, wihT, whhT, rtHi, rtLo, wihHi, wihLo, whhHi, whhLo);
    k_lin0<<<N_NODES / 4, 256, 0, stream>>>(x, lin0_w, lin0_b, out);
    k_deg <<<N_EDGES / 256, 256, 0, stream>>>(ei, degu);
    k_dinv<<<N_NODES / 256, 256, 0, stream>>>(degu, dinv);

    for (int r = 0; r < 3; ++r){
        hipMemsetAsync(agg, 0, (size_t)N_NODES * DIM * 4, stream);
        k_msg_fused<<<N_EDGES / EB, 512, 0, stream>>>(ei, ea, nn1_w, nn1_b, w2T, nn2_b, out, agg);
        k_update   <<<N_NODES / 64, 256, 0, stream>>>(rtHi, rtLo, wihHi, wihLo, whhHi, whhLo,
                        conv_b, gbih, gbhh, agg, dinv, out);
    }

    k_s2s<<<NGRAPH, 256, 0, stream>>>(out, batch, wihT, lbih, whhT, lbhh,
                l1w, l1b, l2w, l2b, y);
}